// Round 2
// baseline (134.878 us; speedup 1.0000x reference)
//
#include <hip/hip_runtime.h>
#include <hip/hip_bf16.h>

#define B_ 4
#define T_ 128
#define U_ 64
#define D_ 512
#define H_ 640
#define V_ 1024

typedef float f32x4 __attribute__((ext_vector_type(4)));
typedef __bf16 bf16x8 __attribute__((ext_vector_type(8)));

union U4BF8 { uint4 u; bf16x8 v; };

__device__ __forceinline__ unsigned short f2bf(float x) {
  union { float f; unsigned int u; } a; a.f = x;
  unsigned int r = a.u + 0x7FFFu + ((a.u >> 16) & 1u);
  return (unsigned short)(r >> 16);
}

// ---------------------------------------------------------------------------
// P0: pack W2 (H x V f32) into bf16 fragment layout: cell(kq, n) holds
// W2[8kq .. 8kq+7][n] as 8 contiguous bf16 (one 16B dwordx4 per MFMA B-frag
// lane). Also writes the two length vectors (as float) into the d_out tail.
// ---------------------------------------------------------------------------
__global__ void k_pack_w2(const float* __restrict__ W2, uint4* __restrict__ w2p,
                          const int* __restrict__ slen, const int* __restrict__ tlen,
                          float* __restrict__ out_tail) {
  int kq = blockIdx.x;           // 0..79
  int tid = threadIdx.x;         // 256
  for (int i = 0; i < 4; ++i) {
    int n = tid + i * 256;
    float f[8];
    #pragma unroll
    for (int j = 0; j < 8; ++j) f[j] = W2[(size_t)(kq * 8 + j) * V_ + n];
    unsigned int w[4];
    #pragma unroll
    for (int j = 0; j < 4; ++j)
      w[j] = (unsigned)f2bf(f[2 * j]) | ((unsigned)f2bf(f[2 * j + 1]) << 16);
    uint4 p; p.x = w[0]; p.y = w[1]; p.z = w[2]; p.w = w[3];
    w2p[kq * V_ + n] = p;
  }
  if (blockIdx.x == 0 && tid < 8)
    out_tail[tid] = (tid < 4) ? (float)slen[tid] : (float)tlen[tid - 4];
}

// ---------------------------------------------------------------------------
// P1: ps = SRC @ W1[:D]  (512x640);  pt = TGT @ W1[D:] + b1  (256x640), f32.
// ---------------------------------------------------------------------------
__global__ __launch_bounds__(640) void k_proj(
    const float* __restrict__ src, const float* __restrict__ tgt,
    const float* __restrict__ W1, const float* __restrict__ b1,
    float* __restrict__ ps, float* __restrict__ pt) {
  __shared__ __align__(16) float lin[D_ * 4];
  int bid = blockIdx.x, tid = threadIdx.x;
  bool is_t = bid >= 128;
  const float* in; const float* w; float* outp;
  if (!is_t) {
    int r0 = bid * 4;
    in = src + (size_t)r0 * D_; w = W1; outp = ps + (size_t)r0 * H_;
  } else {
    int r0 = (bid - 128) * 4;
    in = tgt + (size_t)r0 * D_; w = W1 + (size_t)D_ * H_; outp = pt + (size_t)r0 * H_;
  }
  for (int idx = tid; idx < 4 * D_; idx += 640) {
    int r = idx >> 9, k = idx & (D_ - 1);
    lin[k * 4 + r] = in[idx];
  }
  __syncthreads();
  float a0 = 0.f, a1 = 0.f, a2 = 0.f, a3 = 0.f;
  int j = tid;
  for (int k = 0; k < D_; ++k) {
    float wv = w[(size_t)k * H_ + j];
    f32x4 x = *(const f32x4*)&lin[k * 4];
    a0 += x[0] * wv; a1 += x[1] * wv; a2 += x[2] * wv; a3 += x[3] * wv;
  }
  float bb = is_t ? b1[j] : 0.f;
  outp[0 * H_ + j] = a0 + bb;
  outp[1 * H_ + j] = a1 + bb;
  outp[2 * H_ + j] = a2 + bb;
  outp[3 * H_ + j] = a3 + bb;
}

// ---------------------------------------------------------------------------
// Main: one block per (b, t), 1024 threads = 16 waves.
// Wave w owns all 64 rows x 64 cols [w*64, w*64+64): acc = 16 f32x4 = 64
// regs/thread -> with __launch_bounds__(1024,4) total regs <=128 ->
// 4 waves/SIMD (16 waves/CU, 50% occupancy) vs round-1's 2/SIMD.
// B-dedup preserved: 16 waves x 64 cols = V, W2 L2 traffic unchanged.
// Phase 1: A[u,k]=tanh(ps[k]+pt[u,k]) -> bf16 LDS (80 KiB, full K).
// Phase 2: 16x16x32 bf16 MFMA, K=640, B streamed from L2.
// Phase 3: +b2, two-level log_softmax (16-lane shuffle, 16-wave LDS combine).
// ---------------------------------------------------------------------------
__global__ __launch_bounds__(1024, 4) void k_joint(
    const float* __restrict__ ps, const float* __restrict__ pt,
    const uint4* __restrict__ w2p, const float* __restrict__ b2,
    float* __restrict__ out) {
  __shared__ uint4 ldsA[80 * 64];          // 80 KiB
  __shared__ float red[64][16][2];         // 8 KiB
  int bid = blockIdx.x;
  int b = bid >> 7, t = bid & 127;
  int tid = threadIdx.x;
  const float* psrow = ps + (size_t)(b * T_ + t) * H_;
  const float* ptb   = pt + (size_t)(b * U_) * H_;

  // ---- phase 1: A generation (5 cells/thread) ----
  for (int c = tid; c < 80 * 64; c += 1024) {
    int m = c / 80, kq = c - m * 80;       // consecutive tids -> consecutive kq
    const float4* pp = (const float4*)(psrow + kq * 8);
    const float4* qq = (const float4*)(ptb + (size_t)m * H_ + kq * 8);
    float4 p0 = pp[0], p1 = pp[1];
    float4 q0 = qq[0], q1 = qq[1];
    float x[8] = {p0.x + q0.x, p0.y + q0.y, p0.z + q0.z, p0.w + q0.w,
                  p1.x + q1.x, p1.y + q1.y, p1.z + q1.z, p1.w + q1.w};
    unsigned int wv[4];
    #pragma unroll
    for (int j = 0; j < 4; ++j) {
      float e0 = __expf(2.f * x[2 * j]);
      float h0 = 1.f - 2.f * __builtin_amdgcn_rcpf(e0 + 1.f);
      float e1 = __expf(2.f * x[2 * j + 1]);
      float h1 = 1.f - 2.f * __builtin_amdgcn_rcpf(e1 + 1.f);
      wv[j] = (unsigned)f2bf(h0) | ((unsigned)f2bf(h1) << 16);
    }
    uint4 pk; pk.x = wv[0]; pk.y = wv[1]; pk.z = wv[2]; pk.w = wv[3];
    ldsA[kq * 64 + (m ^ (kq & 7))] = pk;
  }
  __syncthreads();

  int lane = tid & 63, wid = tid >> 6;      // wid 0..15
  int l16 = lane & 15, lg = lane >> 4;

  f32x4 acc[4][4];
  #pragma unroll
  for (int mf = 0; mf < 4; ++mf)
    #pragma unroll
    for (int nf = 0; nf < 4; ++nf) {
      f32x4 z = {0.f, 0.f, 0.f, 0.f};
      acc[mf][nf] = z;
    }

  // ---- phase 2: K loop (20 steps of K=32) ----
  for (int kq0 = 0; kq0 < 80; kq0 += 4) {
    int kq = kq0 + lg;
    U4BF8 a[4];
    #pragma unroll
    for (int mf = 0; mf < 4; ++mf)
      a[mf].u = ldsA[kq * 64 + ((mf * 16 + l16) ^ (kq & 7))];
    const uint4* bp = w2p + kq * 1024 + wid * 64 + l16;
    #pragma unroll
    for (int nf = 0; nf < 4; ++nf) {
      U4BF8 bb; bb.u = bp[nf * 16];
      #pragma unroll
      for (int mf = 0; mf < 4; ++mf)
        acc[mf][nf] = __builtin_amdgcn_mfma_f32_16x16x32_bf16(
            a[mf].v, bb.v, acc[mf][nf], 0, 0, 0);
    }
  }

  // ---- phase 3: +b2, log_softmax, store ----
  float b2v[4];
  #pragma unroll
  for (int nf = 0; nf < 4; ++nf) b2v[nf] = b2[wid * 64 + nf * 16 + l16];

  #pragma unroll
  for (int mf = 0; mf < 4; ++mf)
    #pragma unroll
    for (int r = 0; r < 4; ++r) {
      float pm = -3.4e38f;
      #pragma unroll
      for (int nf = 0; nf < 4; ++nf) pm = fmaxf(pm, acc[mf][nf][r] + b2v[nf]);
      pm = fmaxf(pm, __shfl_xor(pm, 1));
      pm = fmaxf(pm, __shfl_xor(pm, 2));
      pm = fmaxf(pm, __shfl_xor(pm, 4));
      pm = fmaxf(pm, __shfl_xor(pm, 8));
      float s = 0.f;
      #pragma unroll
      for (int nf = 0; nf < 4; ++nf) s += __expf(acc[mf][nf][r] + b2v[nf] - pm);
      s += __shfl_xor(s, 1);
      s += __shfl_xor(s, 2);
      s += __shfl_xor(s, 4);
      s += __shfl_xor(s, 8);
      if (l16 == 0) {
        int row = mf * 16 + lg * 4 + r;
        red[row][wid][0] = pm;
        red[row][wid][1] = s;
      }
    }
  __syncthreads();

  float* outb = out + (size_t)(b * T_ + t) * U_ * V_;
  #pragma unroll
  for (int mf = 0; mf < 4; ++mf)
    #pragma unroll
    for (int r = 0; r < 4; ++r) {
      int row = mf * 16 + lg * 4 + r;
      float M = -3.4e38f;
      #pragma unroll
      for (int w16 = 0; w16 < 16; ++w16) M = fmaxf(M, red[row][w16][0]);
      float S = 0.f;
      #pragma unroll
      for (int w16 = 0; w16 < 16; ++w16)
        S += red[row][w16][1] * __expf(red[row][w16][0] - M);
      float lz = M + __logf(S);
      float* orow = outb + (size_t)row * V_ + wid * 64 + l16;
      #pragma unroll
      for (int nf = 0; nf < 4; ++nf)
        orow[nf * 16] = acc[mf][nf][r] + b2v[nf] - lz;
    }
}

extern "C" void kernel_launch(void* const* d_in, const int* in_sizes, int n_in,
                              void* d_out, int out_size, void* d_ws, size_t ws_size,
                              hipStream_t stream) {
  const float* src = (const float*)d_in[0];
  const int*   slen = (const int*)d_in[1];
  const float* tgt = (const float*)d_in[2];
  const int*   tlen = (const int*)d_in[3];
  const float* W1 = (const float*)d_in[4];
  const float* b1 = (const float*)d_in[5];
  const float* W2 = (const float*)d_in[6];
  const float* b2 = (const float*)d_in[7];
  float* out = (float*)d_out;

  float* ps  = (float*)d_ws;                 // 512*640 f32
  float* pt  = ps + 512 * 640;               // 256*640 f32
  uint4* w2p = (uint4*)(pt + 256 * 640);     // 80*1024 uint4 (bf16 packed W2)

  k_pack_w2<<<80, 256, 0, stream>>>(W2, w2p, slen, tlen,
                                    out + (size_t)B_ * T_ * U_ * V_);
  k_proj<<<192, 640, 0, stream>>>(src, tgt, W1, b1, ps, pt);
  k_joint<<<512, 1024, 0, stream>>>(ps, pt, w2p, b2, out);
}

// Round 3
// 109.370 us; speedup vs baseline: 1.2332x; 1.2332x over previous
//
#include <hip/hip_runtime.h>
#include <hip/hip_bf16.h>

#define B_ 4
#define T_ 128
#define U_ 64
#define D_ 512
#define H_ 640
#define V_ 1024

typedef float f32x4 __attribute__((ext_vector_type(4)));
typedef __bf16 bf16x8 __attribute__((ext_vector_type(8)));

union U4BF8 { uint4 u; bf16x8 v; };

__device__ __forceinline__ unsigned short f2bf(float x) {
  union { float f; unsigned int u; } a; a.f = x;
  unsigned int r = a.u + 0x7FFFu + ((a.u >> 16) & 1u);
  return (unsigned short)(r >> 16);
}

// ---------------------------------------------------------------------------
// P0: pack W2 (H x V f32) into bf16 fragment layout: cell(kq, n) holds
// W2[8kq .. 8kq+7][n] as 8 contiguous bf16 (one 16B dwordx4 per MFMA B-frag
// lane). Also writes the two length vectors (as float) into the d_out tail.
// ---------------------------------------------------------------------------
__global__ void k_pack_w2(const float* __restrict__ W2, uint4* __restrict__ w2p,
                          const int* __restrict__ slen, const int* __restrict__ tlen,
                          float* __restrict__ out_tail) {
  int kq = blockIdx.x;           // 0..79
  int tid = threadIdx.x;         // 256
  for (int i = 0; i < 4; ++i) {
    int n = tid + i * 256;
    float f[8];
    #pragma unroll
    for (int j = 0; j < 8; ++j) f[j] = W2[(size_t)(kq * 8 + j) * V_ + n];
    unsigned int w[4];
    #pragma unroll
    for (int j = 0; j < 4; ++j)
      w[j] = (unsigned)f2bf(f[2 * j]) | ((unsigned)f2bf(f[2 * j + 1]) << 16);
    uint4 p; p.x = w[0]; p.y = w[1]; p.z = w[2]; p.w = w[3];
    w2p[kq * V_ + n] = p;
  }
  if (blockIdx.x == 0 && tid < 8)
    out_tail[tid] = (tid < 4) ? (float)slen[tid] : (float)tlen[tid - 4];
}

// ---------------------------------------------------------------------------
// P1: ps = SRC @ W1[:D]  (512x640);  pt = TGT @ W1[D:] + b1  (256x640), f32.
// ---------------------------------------------------------------------------
__global__ __launch_bounds__(640) void k_proj(
    const float* __restrict__ src, const float* __restrict__ tgt,
    const float* __restrict__ W1, const float* __restrict__ b1,
    float* __restrict__ ps, float* __restrict__ pt) {
  __shared__ __align__(16) float lin[D_ * 4];
  int bid = blockIdx.x, tid = threadIdx.x;
  bool is_t = bid >= 128;
  const float* in; const float* w; float* outp;
  if (!is_t) {
    int r0 = bid * 4;
    in = src + (size_t)r0 * D_; w = W1; outp = ps + (size_t)r0 * H_;
  } else {
    int r0 = (bid - 128) * 4;
    in = tgt + (size_t)r0 * D_; w = W1 + (size_t)D_ * H_; outp = pt + (size_t)r0 * H_;
  }
  for (int idx = tid; idx < 4 * D_; idx += 640) {
    int r = idx >> 9, k = idx & (D_ - 1);
    lin[k * 4 + r] = in[idx];
  }
  __syncthreads();
  float a0 = 0.f, a1 = 0.f, a2 = 0.f, a3 = 0.f;
  int j = tid;
  for (int k = 0; k < D_; ++k) {
    float wv = w[(size_t)k * H_ + j];
    f32x4 x = *(const f32x4*)&lin[k * 4];
    a0 += x[0] * wv; a1 += x[1] * wv; a2 += x[2] * wv; a3 += x[3] * wv;
  }
  float bb = is_t ? b1[j] : 0.f;
  outp[0 * H_ + j] = a0 + bb;
  outp[1 * H_ + j] = a1 + bb;
  outp[2 * H_ + j] = a2 + bb;
  outp[3 * H_ + j] = a3 + bb;
}

// ---------------------------------------------------------------------------
// Main: one block per (b, t), 1024 threads = 16 waves.
// LDS A layout: cell(m, kq) at ldsA[m*80 + (kq ^ (m&7))].
//   - gen writes (consecutive lanes = consecutive kq, m fixed): contiguous
//     cells -> conflict-free ds_write_b128.
//   - MFMA frag reads (kq fixed, m = mf*16+l16): bank group =
//     4*((kq%8)^(l16&7)) -> each group hit exactly 2x (free per m136).
// Phase 3: per-lane-group reduce -> red[row][wid]; ONE owner thread per row
// combines the 16 wave partials into lz (was: all 1024 threads redundantly,
// 262K exps + 512K LDS reads per block).
// ---------------------------------------------------------------------------
__global__ __launch_bounds__(1024, 4) void k_joint(
    const float* __restrict__ ps, const float* __restrict__ pt,
    const uint4* __restrict__ w2p, const float* __restrict__ b2,
    float* __restrict__ out) {
  __shared__ uint4 ldsA[80 * 64];          // 80 KiB
  __shared__ float red[64][16][2];         // 8 KiB
  __shared__ float lzs[64];
  int bid = blockIdx.x;
  int b = bid >> 7, t = bid & 127;
  int tid = threadIdx.x;
  const float* psrow = ps + (size_t)(b * T_ + t) * H_;
  const float* ptb   = pt + (size_t)(b * U_) * H_;

  // ---- phase 1: A generation (5 cells/thread) ----
  for (int c = tid; c < 80 * 64; c += 1024) {
    int m = c / 80, kq = c - m * 80;       // consecutive tids -> consecutive kq
    const float4* pp = (const float4*)(psrow + kq * 8);
    const float4* qq = (const float4*)(ptb + (size_t)m * H_ + kq * 8);
    float4 p0 = pp[0], p1 = pp[1];
    float4 q0 = qq[0], q1 = qq[1];
    float x[8] = {p0.x + q0.x, p0.y + q0.y, p0.z + q0.z, p0.w + q0.w,
                  p1.x + q1.x, p1.y + q1.y, p1.z + q1.z, p1.w + q1.w};
    unsigned int wv[4];
    #pragma unroll
    for (int j = 0; j < 4; ++j) {
      float e0 = __expf(2.f * x[2 * j]);
      float h0 = 1.f - 2.f * __builtin_amdgcn_rcpf(e0 + 1.f);
      float e1 = __expf(2.f * x[2 * j + 1]);
      float h1 = 1.f - 2.f * __builtin_amdgcn_rcpf(e1 + 1.f);
      wv[j] = (unsigned)f2bf(h0) | ((unsigned)f2bf(h1) << 16);
    }
    uint4 pk; pk.x = wv[0]; pk.y = wv[1]; pk.z = wv[2]; pk.w = wv[3];
    ldsA[m * 80 + (kq ^ (m & 7))] = pk;
  }
  __syncthreads();

  int lane = tid & 63, wid = tid >> 6;      // wid 0..15
  int l16 = lane & 15, lg = lane >> 4;
  int xs = l16 & 7;

  f32x4 acc[4][4];
  #pragma unroll
  for (int mf = 0; mf < 4; ++mf)
    #pragma unroll
    for (int nf = 0; nf < 4; ++nf) {
      f32x4 z = {0.f, 0.f, 0.f, 0.f};
      acc[mf][nf] = z;
    }

  // ---- phase 2: K loop (20 steps of K=32), B streamed from L2 ----
  for (int kq0 = 0; kq0 < 80; kq0 += 4) {
    int kq = kq0 + lg;
    int kqx = kq ^ xs;
    U4BF8 a[4];
    #pragma unroll
    for (int mf = 0; mf < 4; ++mf)
      a[mf].u = ldsA[(mf * 16 + l16) * 80 + kqx];
    const uint4* bp = w2p + (size_t)kq * 1024 + wid * 64 + l16;
    #pragma unroll
    for (int nf = 0; nf < 4; ++nf) {
      U4BF8 bb; bb.u = bp[nf * 16];
      #pragma unroll
      for (int mf = 0; mf < 4; ++mf)
        acc[mf][nf] = __builtin_amdgcn_mfma_f32_16x16x32_bf16(
            a[mf].v, bb.v, acc[mf][nf], 0, 0, 0);
    }
  }

  // ---- phase 3: fold b2 once, reduce, one lz per row, store ----
  {
    float b2v[4];
    #pragma unroll
    for (int nf = 0; nf < 4; ++nf) b2v[nf] = b2[wid * 64 + nf * 16 + l16];
    #pragma unroll
    for (int mf = 0; mf < 4; ++mf)
      #pragma unroll
      for (int nf = 0; nf < 4; ++nf)
        #pragma unroll
        for (int r = 0; r < 4; ++r)
          acc[mf][nf][r] += b2v[nf];
  }

  #pragma unroll
  for (int mf = 0; mf < 4; ++mf)
    #pragma unroll
    for (int r = 0; r < 4; ++r) {
      float pm = -3.4e38f;
      #pragma unroll
      for (int nf = 0; nf < 4; ++nf) pm = fmaxf(pm, acc[mf][nf][r]);
      pm = fmaxf(pm, __shfl_xor(pm, 1));
      pm = fmaxf(pm, __shfl_xor(pm, 2));
      pm = fmaxf(pm, __shfl_xor(pm, 4));
      pm = fmaxf(pm, __shfl_xor(pm, 8));
      float s = 0.f;
      #pragma unroll
      for (int nf = 0; nf < 4; ++nf) s += __expf(acc[mf][nf][r] - pm);
      s += __shfl_xor(s, 1);
      s += __shfl_xor(s, 2);
      s += __shfl_xor(s, 4);
      s += __shfl_xor(s, 8);
      if (l16 == 0) {
        int row = mf * 16 + lg * 4 + r;
        red[row][wid][0] = pm;
        red[row][wid][1] = s;
      }
    }
  __syncthreads();

  // one thread per row combines the 16 wave partials
  if (tid < 64) {
    float M = -3.4e38f;
    #pragma unroll
    for (int w16 = 0; w16 < 16; ++w16) M = fmaxf(M, red[tid][w16][0]);
    float S = 0.f;
    #pragma unroll
    for (int w16 = 0; w16 < 16; ++w16)
      S += red[tid][w16][1] * __expf(red[tid][w16][0] - M);
    lzs[tid] = M + __logf(S);
  }
  __syncthreads();

  float* outb = out + (size_t)(b * T_ + t) * U_ * V_;
  #pragma unroll
  for (int mf = 0; mf < 4; ++mf)
    #pragma unroll
    for (int r = 0; r < 4; ++r) {
      int row = mf * 16 + lg * 4 + r;
      float lz = lzs[row];
      float* orow = outb + (size_t)row * V_ + wid * 64 + l16;
      #pragma unroll
      for (int nf = 0; nf < 4; ++nf)
        orow[nf * 16] = acc[mf][nf][r] - lz;
    }
}

extern "C" void kernel_launch(void* const* d_in, const int* in_sizes, int n_in,
                              void* d_out, int out_size, void* d_ws, size_t ws_size,
                              hipStream_t stream) {
  const float* src = (const float*)d_in[0];
  const int*   slen = (const int*)d_in[1];
  const float* tgt = (const float*)d_in[2];
  const int*   tlen = (const int*)d_in[3];
  const float* W1 = (const float*)d_in[4];
  const float* b1 = (const float*)d_in[5];
  const float* W2 = (const float*)d_in[6];
  const float* b2 = (const float*)d_in[7];
  float* out = (float*)d_out;

  float* ps  = (float*)d_ws;                 // 512*640 f32
  float* pt  = ps + 512 * 640;               // 256*640 f32
  uint4* w2p = (uint4*)(pt + 256 * 640);     // 80*1024 uint4 (bf16 packed W2)

  k_pack_w2<<<80, 256, 0, stream>>>(W2, w2p, slen, tlen,
                                    out + (size_t)B_ * T_ * U_ * V_);
  k_proj<<<192, 640, 0, stream>>>(src, tgt, W1, b1, ps, pt);
  k_joint<<<512, 1024, 0, stream>>>(ps, pt, w2p, b2, out);
}